// Round 2
// baseline (138.238 us; speedup 1.0000x reference)
//
#include <hip/hip_runtime.h>

#define HH 32          // LSTM size
#define TT 20          // total steps (14 kernel + 3 down + 3 up)

__device__ __forceinline__ float sigmoidf_(float x) {
    return 1.0f / (1.0f + expf(-x));
}

__global__ __launch_bounds__(128) void controller_kernel(
    const float* __restrict__ w_ih,      // [128,32]
    const float* __restrict__ w_hh,      // [128,32]
    const float* __restrict__ b_ih,      // [128]
    const float* __restrict__ b_hh,      // [128]
    const float* __restrict__ g_emb,     // [1,32]
    const float* __restrict__ emb_kernel,// [8,32]
    const float* __restrict__ emb_down,  // [3,32]
    const float* __restrict__ emb_up,    // [3,32]
    const float* __restrict__ w_kernel,  // [8,32]
    const float* __restrict__ w_down,    // [3,32]
    const float* __restrict__ w_up,      // [3,32]
    const float* __restrict__ noise,     // [20,8]
    float* __restrict__ out)             // [22] = stats[2] ++ samples[20]
{
    const int t = threadIdx.x;   // 0..127, one gate row per thread

    __shared__ float x_s[HH];
    __shared__ float h_s[HH];
    __shared__ float c_s[HH];
    __shared__ float gates_s[4 * HH];
    __shared__ float logits_s[8];
    __shared__ int   samp_s;

    // ---- one-time weight preload into registers ----
    float wih[HH], whh[HH];
#pragma unroll
    for (int j = 0; j < HH; ++j) {
        wih[j] = w_ih[t * HH + j];
        whh[j] = w_hh[t * HH + j];
    }
    const float bias = b_ih[t] + b_hh[t];

    if (t < HH) {
        x_s[t] = g_emb[t];
        h_s[t] = 0.0f;
        c_s[t] = 0.0f;
    }
    __syncthreads();

    float lp_sum = 0.0f, ent_sum = 0.0f;   // meaningful on thread 0 only

    for (int step = 0; step < TT; ++step) {
        // ---- A: gates[t] = b + w_ih[t,:]·x + w_hh[t,:]·h ----
        float acc = bias;
#pragma unroll
        for (int j = 0; j < HH; ++j) {
            acc += wih[j] * x_s[j];
            acc += whh[j] * h_s[j];
        }
        gates_s[t] = acc;
        __syncthreads();

        // ---- B: LSTM cell update (torch gate order i,f,g,o) ----
        if (t < HH) {
            const float ig = sigmoidf_(gates_s[t]);
            const float fg = sigmoidf_(gates_s[HH + t]);
            const float gg = tanhf(gates_s[2 * HH + t]);
            const float og = sigmoidf_(gates_s[3 * HH + t]);
            const float c  = fg * c_s[t] + ig * gg;
            c_s[t] = c;
            h_s[t] = og * tanhf(c);
        }
        __syncthreads();

        // per-step head / embedding / class count
        const float* Wp;
        const float* Et;
        int n;
        if (step < 14)      { Wp = w_kernel; Et = emb_kernel; n = 8; }
        else if (step < 17) { Wp = w_down;   Et = emb_down;   n = 3; }
        else                { Wp = w_up;     Et = emb_up;     n = 3; }

        // ---- C: logits (threads 0..7) ----
        if (t < 8) {
            float l = -1e9f;                      // NEG for masked classes
            if (t < n) {
                l = 0.0f;
#pragma unroll
                for (int j = 0; j < HH; ++j)
                    l += Wp[t * HH + j] * h_s[j];
            }
            logits_s[t] = l;
        }
        __syncthreads();

        // ---- D: softmax stats + Gumbel-max sample (thread 0) ----
        if (t == 0) {
            float m = -1e30f;
            for (int k = 0; k < n; ++k) m = fmaxf(m, logits_s[k]);
            float sum = 0.0f;
            for (int k = 0; k < n; ++k) sum += expf(logits_s[k] - m);
            const float lse = m + logf(sum);

            int   best  = 0;
            float bestv = -1e30f;
            for (int k = 0; k < n; ++k) {
                const float u   = noise[step * 8 + k];
                const float gmb = -logf(-logf(u * (1.0f - 1e-6f) + 1e-7f));
                const float v   = logits_s[k] + gmb;
                if (v > bestv) { bestv = v; best = k; }   // first-index tie rule
            }

            lp_sum += logits_s[best] - lse;
            float ent = 0.0f;
            for (int k = 0; k < n; ++k) {
                const float lpk = logits_s[k] - lse;
                ent -= expf(lpk) * lpk;
            }
            ent_sum += ent;

            samp_s = best;
            out[2 + step] = (float)best;
        }
        __syncthreads();

        // ---- E: next-step input x = Et[sample] ----
        if (t < HH) x_s[t] = Et[samp_s * HH + t];
        __syncthreads();
    }

    if (t == 0) {
        out[0] = lp_sum;
        out[1] = ent_sum;
    }
}

extern "C" void kernel_launch(void* const* d_in, const int* in_sizes, int n_in,
                              void* d_out, int out_size, void* d_ws, size_t ws_size,
                              hipStream_t stream) {
    (void)in_sizes; (void)n_in; (void)out_size; (void)d_ws; (void)ws_size;
    const float* w_ih       = (const float*)d_in[0];
    const float* w_hh       = (const float*)d_in[1];
    const float* b_ih       = (const float*)d_in[2];
    const float* b_hh       = (const float*)d_in[3];
    const float* g_emb      = (const float*)d_in[4];
    const float* emb_kernel = (const float*)d_in[5];
    const float* emb_down   = (const float*)d_in[6];
    const float* emb_up     = (const float*)d_in[7];
    const float* w_kernel   = (const float*)d_in[8];
    const float* w_down     = (const float*)d_in[9];
    const float* w_up       = (const float*)d_in[10];
    const float* noise      = (const float*)d_in[11];
    float* out = (float*)d_out;

    hipLaunchKernelGGL(controller_kernel, dim3(1), dim3(128), 0, stream,
                       w_ih, w_hh, b_ih, b_hh, g_emb, emb_kernel, emb_down,
                       emb_up, w_kernel, w_down, w_up, noise, out);
}

// Round 3
// 107.287 us; speedup vs baseline: 1.2885x; 1.2885x over previous
//
#include <hip/hip_runtime.h>

#define HH 32          // LSTM size
#define TT 20          // total steps (14 kernel + 3 down + 3 up)

__device__ __forceinline__ float sigmoidf_(float x) {
    return 1.0f / (1.0f + expf(-x));
}

// One block, ONE wave (64 lanes). Lane t owns gate rows t and t+64, with the
// corresponding w_ih/w_hh rows held in 128 VGPRs. State vector xh = [x;h] (64)
// lives in LDS; c lives in registers of lanes 0..31. Heads/embeddings/Gumbel
// noise are staged into LDS once before the loop.
__global__ __launch_bounds__(64, 1) void controller_kernel(
    const float* __restrict__ w_ih,      // [128,32]
    const float* __restrict__ w_hh,      // [128,32]
    const float* __restrict__ b_ih,      // [128]
    const float* __restrict__ b_hh,      // [128]
    const float* __restrict__ g_emb,     // [1,32]
    const float* __restrict__ emb_kernel,// [8,32]
    const float* __restrict__ emb_down,  // [3,32]
    const float* __restrict__ emb_up,    // [3,32]
    const float* __restrict__ w_kernel,  // [8,32]
    const float* __restrict__ w_down,    // [3,32]
    const float* __restrict__ w_up,      // [3,32]
    const float* __restrict__ noise,     // [20,8]
    float* __restrict__ out)             // [22] = stats[2] ++ samples[20]
{
    const int t = threadIdx.x;   // 0..63

    __shared__ __align__(16) float xh_s[64];     // [0..31]=x, [32..63]=h
    __shared__ float head_t[32 * 16];            // transposed heads: [j][row], stride 16 (14 rows used)
    __shared__ float emb_s[14 * 32];             // embedding rows: 0..7 kernel, 8..10 down, 11..13 up
    __shared__ float gum_s[TT * 8];              // precomputed Gumbel noise

    // ---- one-time weight preload: rows t and t+64, [w_ih_row ; w_hh_row] ----
    float w0[64], w1[64];
    {
        const float4* i0 = (const float4*)(w_ih + t * HH);
        const float4* h0 = (const float4*)(w_hh + t * HH);
        const float4* i1 = (const float4*)(w_ih + (t + 64) * HH);
        const float4* h1 = (const float4*)(w_hh + (t + 64) * HH);
#pragma unroll
        for (int q = 0; q < 8; ++q) {
            float4 a = i0[q]; w0[q*4+0]=a.x; w0[q*4+1]=a.y; w0[q*4+2]=a.z; w0[q*4+3]=a.w;
            float4 b = h0[q]; w0[32+q*4+0]=b.x; w0[32+q*4+1]=b.y; w0[32+q*4+2]=b.z; w0[32+q*4+3]=b.w;
            float4 c = i1[q]; w1[q*4+0]=c.x; w1[q*4+1]=c.y; w1[q*4+2]=c.z; w1[q*4+3]=c.w;
            float4 d = h1[q]; w1[32+q*4+0]=d.x; w1[32+q*4+1]=d.y; w1[32+q*4+2]=d.z; w1[32+q*4+3]=d.w;
        }
    }
    const float bias0 = b_ih[t] + b_hh[t];
    const float bias1 = b_ih[t + 64] + b_hh[t + 64];

    // ---- stage heads (transposed), embeddings, Gumbel noise into LDS ----
    for (int idx = t; idx < 14 * 32; idx += 64) {
        const int r = idx >> 5, j = idx & 31;
        float hv, ev;
        if (r < 8)       { hv = w_kernel[r * 32 + j];        ev = emb_kernel[r * 32 + j]; }
        else if (r < 11) { hv = w_down[(r - 8) * 32 + j];    ev = emb_down[(r - 8) * 32 + j]; }
        else             { hv = w_up[(r - 11) * 32 + j];     ev = emb_up[(r - 11) * 32 + j]; }
        head_t[j * 16 + r] = hv;     // transposed, padded stride: conflict-free by row
        emb_s[idx] = ev;
    }
    for (int idx = t; idx < TT * 8; idx += 64) {
        const float u = noise[idx];
        gum_s[idx] = -logf(-logf(u * (1.0f - 1e-6f) + 1e-7f));
    }
    if (t < HH) xh_s[t] = g_emb[t];
    else        xh_s[t] = 0.0f;      // h = 0
    float c_reg = 0.0f;              // c (lanes 0..31)
    __syncthreads();

    float lp_sum = 0.0f, ent_sum = 0.0f;   // lane 0 only

    const float4* xh4 = (const float4*)xh_s;

    for (int step = 0; step < TT; ++step) {
        // ---- A: gates rows t and t+64 (all 64 lanes) ----
        float a0 = bias0, a0b = 0.0f, a1 = bias1, a1b = 0.0f;
#pragma unroll
        for (int q = 0; q < 16; ++q) {
            const float4 u = xh4[q];
            const int j = q * 4;
            if (q & 1) {
                a0b += w0[j+0]*u.x; a0b += w0[j+1]*u.y; a0b += w0[j+2]*u.z; a0b += w0[j+3]*u.w;
                a1b += w1[j+0]*u.x; a1b += w1[j+1]*u.y; a1b += w1[j+2]*u.z; a1b += w1[j+3]*u.w;
            } else {
                a0 += w0[j+0]*u.x; a0 += w0[j+1]*u.y; a0 += w0[j+2]*u.z; a0 += w0[j+3]*u.w;
                a1 += w1[j+0]*u.x; a1 += w1[j+1]*u.y; a1 += w1[j+2]*u.z; a1 += w1[j+3]*u.w;
            }
        }
        a0 += a0b; a1 += a1b;

        // f and o gates live on lane (t&31)+32; shuffles executed by ALL lanes
        const float fo0 = __shfl(a0, (t & 31) + 32);   // row (t&31)+32  (f gate)
        const float fo1 = __shfl(a1, (t & 31) + 32);   // row (t&31)+96  (o gate)

        // ---- B: LSTM cell (lanes 0..31): i=a0, g=a1, f=fo0, o=fo1 ----
        if (t < HH) {
            const float ig = sigmoidf_(a0);
            const float fg = sigmoidf_(fo0);
            const float gg = tanhf(a1);
            const float og = sigmoidf_(fo1);
            c_reg = fg * c_reg + ig * gg;
            xh_s[HH + t] = og * tanhf(c_reg);
        }
        __syncthreads();

        // per-step head/emb row base and class count
        const int n     = (step < 14) ? 8 : 3;
        const int rbase = (step < 14) ? 0 : ((step < 17) ? 8 : 11);

        // ---- C: logits on lanes 0..7 (head from transposed LDS, h broadcast) ----
        float l = -1e9f;
        if (t < 8 && t < n) {
            float s0 = 0.0f, s1 = 0.0f;
#pragma unroll
            for (int j = 0; j < HH; j += 2) {
                s0 += head_t[j * 16 + rbase + t]       * xh_s[HH + j];
                s1 += head_t[(j + 1) * 16 + rbase + t] * xh_s[HH + j + 1];
            }
            l = s0 + s1;
        }

        // ---- D: softmax stats + Gumbel argmax via shfl_xor butterflies (groups of 8) ----
        float m = l;
#pragma unroll
        for (int msk = 1; msk <= 4; msk <<= 1) m = fmaxf(m, __shfl_xor(m, msk));

        const float e  = expf(l - m);        // masked lanes: exp(-1e9-m) = 0
        float S = e, T = e * l;
#pragma unroll
        for (int msk = 1; msk <= 4; msk <<= 1) {
            S += __shfl_xor(S, msk);
            T += __shfl_xor(T, msk);
        }

        const float g = (t < 8) ? gum_s[step * 8 + t] : 0.0f;
        float v = l + g; int idx = t & 7; float lr = l;
#pragma unroll
        for (int msk = 1; msk <= 4; msk <<= 1) {
            const float ov  = __shfl_xor(v, msk);
            const int   oi  = __shfl_xor(idx, msk);
            const float olr = __shfl_xor(lr, msk);
            const bool take = (ov > v) || (ov == v && oi < idx);  // first-index tie rule
            v = take ? ov : v; idx = take ? oi : idx; lr = take ? olr : lr;
        }

        if (t == 0) {
            const float lse = m + logf(S);
            lp_sum  += lr - lse;
            ent_sum += lse - T / S;          // -sum p*logp == lse - E[l]
            out[2 + step] = (float)idx;
        }
        const int s = __shfl(idx, 0);

        // ---- E: next input x = Et[s] (lanes 0..31) ----
        if (t < HH) xh_s[t] = emb_s[(rbase + s) * 32 + t];
        __syncthreads();
    }

    if (t == 0) {
        out[0] = lp_sum;
        out[1] = ent_sum;
    }
}

extern "C" void kernel_launch(void* const* d_in, const int* in_sizes, int n_in,
                              void* d_out, int out_size, void* d_ws, size_t ws_size,
                              hipStream_t stream) {
    (void)in_sizes; (void)n_in; (void)out_size; (void)d_ws; (void)ws_size;
    const float* w_ih       = (const float*)d_in[0];
    const float* w_hh       = (const float*)d_in[1];
    const float* b_ih       = (const float*)d_in[2];
    const float* b_hh       = (const float*)d_in[3];
    const float* g_emb      = (const float*)d_in[4];
    const float* emb_kernel = (const float*)d_in[5];
    const float* emb_down   = (const float*)d_in[6];
    const float* emb_up     = (const float*)d_in[7];
    const float* w_kernel   = (const float*)d_in[8];
    const float* w_down     = (const float*)d_in[9];
    const float* w_up       = (const float*)d_in[10];
    const float* noise      = (const float*)d_in[11];
    float* out = (float*)d_out;

    hipLaunchKernelGGL(controller_kernel, dim3(1), dim3(64), 0, stream,
                       w_ih, w_hh, b_ih, b_hh, g_emb, emb_kernel, emb_down,
                       emb_up, w_kernel, w_down, w_up, noise, out);
}

// Round 4
// 95.605 us; speedup vs baseline: 1.4459x; 1.1222x over previous
//
#include <hip/hip_runtime.h>

#define HH 32          // LSTM size
#define TT 20          // total steps (14 kernel + 3 down + 3 up)

typedef float v2f __attribute__((ext_vector_type(2)));

#define LOG2E  1.4426950408889634f
#define LN2    0.6931471805599453f

__device__ __forceinline__ float fsig(float x) {
    // 1/(1+e^-x) via hw exp2/rcp
    return __builtin_amdgcn_rcpf(1.0f + __builtin_amdgcn_exp2f(-x * LOG2E));
}
__device__ __forceinline__ float ftanh(float x) {
    // tanh = 1 - 2/(e^{2x}+1)
    return 1.0f - 2.0f * __builtin_amdgcn_rcpf(1.0f + __builtin_amdgcn_exp2f(x * (2.0f * LOG2E)));
}

// One block, ONE wave. Lane t owns gate rows t and t+64 in 128 VGPRs (as
// float2 for v_pk_fma_f32). All transcendentals are raw HW instructions.
// Logits: all 64 lanes compute a 4-elem partial for class (t&7), chunk (t>>3);
// after xor-8/16/32 reduction every lane holds its class logit, and the
// sum/argmax butterfly over xor-1/2/4 leaves the sample index in EVERY lane.
__global__ __launch_bounds__(64, 1) void controller_kernel(
    const float* __restrict__ w_ih,      // [128,32]
    const float* __restrict__ w_hh,      // [128,32]
    const float* __restrict__ b_ih,      // [128]
    const float* __restrict__ b_hh,      // [128]
    const float* __restrict__ g_emb,     // [1,32]
    const float* __restrict__ emb_kernel,// [8,32]
    const float* __restrict__ emb_down,  // [3,32]
    const float* __restrict__ emb_up,    // [3,32]
    const float* __restrict__ w_kernel,  // [8,32]
    const float* __restrict__ w_down,    // [3,32]
    const float* __restrict__ w_up,      // [3,32]
    const float* __restrict__ noise,     // [20,8]
    float* __restrict__ out)             // [22] = stats[2] ++ samples[20]
{
    const int t = threadIdx.x;   // 0..63

    __shared__ __align__(16) float xh_s[64];        // [0..31]=x, [32..63]=h
    __shared__ __align__(16) float head_pre[3 * 64 * 4]; // per-lane head float4, per base
    __shared__ float emb_s[14 * 32];                // rows: 0..7 kernel, 8..10 down, 11..13 up
    __shared__ float gum_s[TT * 8];                 // precomputed Gumbel noise

    // ---- one-time weight preload: rows t and t+64 as float2 pairs ----
    v2f w0[32], w1[32];
    {
        const float4* i0 = (const float4*)(w_ih + t * HH);
        const float4* h0 = (const float4*)(w_hh + t * HH);
        const float4* i1 = (const float4*)(w_ih + (t + 64) * HH);
        const float4* h1 = (const float4*)(w_hh + (t + 64) * HH);
#pragma unroll
        for (int q = 0; q < 8; ++q) {
            float4 a = i0[q]; w0[2*q] = (v2f){a.x, a.y};      w0[2*q+1] = (v2f){a.z, a.w};
            float4 b = h0[q]; w0[16+2*q] = (v2f){b.x, b.y};   w0[16+2*q+1] = (v2f){b.z, b.w};
            float4 c = i1[q]; w1[2*q] = (v2f){c.x, c.y};      w1[2*q+1] = (v2f){c.z, c.w};
            float4 d = h1[q]; w1[16+2*q] = (v2f){d.x, d.y};   w1[16+2*q+1] = (v2f){d.z, d.w};
        }
    }
    const float bias0 = b_ih[t] + b_hh[t];
    const float bias1 = b_ih[t + 64] + b_hh[t + 64];

    // ---- per-lane pre-arranged heads: head_pre[bi][t] = W[rb+(t&7)][(t>>3)*4 ..] ----
#pragma unroll
    for (int bi = 0; bi < 3; ++bi) {
        const int rb  = (bi == 0) ? 0 : ((bi == 1) ? 8 : 11);
        const int row = rb + (t & 7);
        const int ch  = (t >> 3) * 4;
        float4 v = make_float4(0.f, 0.f, 0.f, 0.f);
        if (row < 14) {
            const float* W = (row < 8)  ? (w_kernel + row * 32)
                           : (row < 11) ? (w_down + (row - 8) * 32)
                                        : (w_up + (row - 11) * 32);
            v = *(const float4*)(W + ch);
        }
        *(float4*)(head_pre + (bi * 64 + t) * 4) = v;
    }
    // embeddings
    for (int idx = t; idx < 14 * 32; idx += 64) {
        const int r = idx >> 5, j = idx & 31;
        emb_s[idx] = (r < 8)  ? emb_kernel[r * 32 + j]
                   : (r < 11) ? emb_down[(r - 8) * 32 + j]
                              : emb_up[(r - 11) * 32 + j];
    }
    // Gumbel noise (accurate logf here — off the critical path)
    for (int idx = t; idx < TT * 8; idx += 64) {
        const float u = noise[idx];
        gum_s[idx] = -logf(-logf(u * (1.0f - 1e-6f) + 1e-7f));
    }
    if (t < HH) xh_s[t] = g_emb[t];
    else        xh_s[t] = 0.0f;      // h = 0
    float c_reg = 0.0f;              // c (lanes 0..31)
    __syncthreads();

    float lp_sum = 0.0f, ent_sum = 0.0f;   // identical on all lanes

    const float4* xh4 = (const float4*)xh_s;

    for (int step = 0; step < TT; ++step) {
        // ---- A: gates rows t and t+64, packed-fp32 dot over xh=[x;h] ----
        v2f s0a = {0.f, 0.f}, s0b = {0.f, 0.f}, s1a = {0.f, 0.f}, s1b = {0.f, 0.f};
#pragma unroll
        for (int q = 0; q < 16; ++q) {
            const float4 xv = xh4[q];
            const v2f u0 = {xv.x, xv.y};
            const v2f u1 = {xv.z, xv.w};
            s0a += w0[2*q] * u0;  s0b += w0[2*q+1] * u1;
            s1a += w1[2*q] * u0;  s1b += w1[2*q+1] * u1;
        }
        const float a0 = bias0 + ((s0a.x + s0a.y) + (s0b.x + s0b.y));
        const float a1 = bias1 + ((s1a.x + s1a.y) + (s1b.x + s1b.y));

        // f/o gate rows live on lane t^32 (for lanes 0..31)
        const float fo0 = __shfl_xor(a0, 32);
        const float fo1 = __shfl_xor(a1, 32);

        // ---- B: LSTM cell (lanes 0..31): i=a0, g=a1, f=fo0, o=fo1 ----
        if (t < HH) {
            const float ig = fsig(a0);
            const float fg = fsig(fo0);
            const float gg = ftanh(a1);
            const float og = fsig(fo1);
            c_reg = fg * c_reg + ig * gg;
            xh_s[HH + t] = og * ftanh(c_reg);
        }
        __syncthreads();

        const int n     = (step < 14) ? 8 : 3;
        const int bi    = (step < 14) ? 0 : ((step < 17) ? 1 : 2);
        const int rbase = (step < 14) ? 0 : ((step < 17) ? 8 : 11);

        // ---- C: logits, all lanes: class (t&7), chunk (t>>3) ----
        const float4 hp = *(const float4*)(head_pre + (bi * 64 + t) * 4);
        const float4 hv = *(const float4*)(xh_s + HH + (t >> 3) * 4);
        float p = hp.x * hv.x + hp.y * hv.y + hp.z * hv.z + hp.w * hv.w;
        p += __shfl_xor(p, 8);
        p += __shfl_xor(p, 16);
        p += __shfl_xor(p, 32);
        const float l = ((t & 7) < n) ? p : -1e9f;

        // ---- D: fused sum + argmax butterfly (|l|<3.3 so no max-subtract) ----
        float e = __builtin_amdgcn_exp2f(l * LOG2E);   // masked: underflows to 0
        float S = e, T = e * l;
        float v = l + gum_s[step * 8 + (t & 7)];
        int   idx = t & 7;
        float lr  = l;
#pragma unroll
        for (int m = 1; m <= 4; m <<= 1) {
            S += __shfl_xor(S, m);
            T += __shfl_xor(T, m);
            const float ov  = __shfl_xor(v, m);
            const int   oi  = __shfl_xor(idx, m);
            const float olr = __shfl_xor(lr, m);
            const bool take = (ov > v) || (ov == v && oi < idx);  // first-index tie rule
            v = take ? ov : v; idx = take ? oi : idx; lr = take ? olr : lr;
        }

        const float lse = __builtin_amdgcn_logf(S) * LN2;
        lp_sum  += lr - lse;
        ent_sum += lse - T * __builtin_amdgcn_rcpf(S);   // -sum p*logp == lse - E[l]
        if (t == 0) out[2 + step] = (float)idx;

        // ---- E: next input x = Et[idx] (every lane already has idx) ----
        if (t < HH) xh_s[t] = emb_s[(rbase + idx) * 32 + t];
        __syncthreads();
    }

    if (t == 0) {
        out[0] = lp_sum;
        out[1] = ent_sum;
    }
}

extern "C" void kernel_launch(void* const* d_in, const int* in_sizes, int n_in,
                              void* d_out, int out_size, void* d_ws, size_t ws_size,
                              hipStream_t stream) {
    (void)in_sizes; (void)n_in; (void)out_size; (void)d_ws; (void)ws_size;
    const float* w_ih       = (const float*)d_in[0];
    const float* w_hh       = (const float*)d_in[1];
    const float* b_ih       = (const float*)d_in[2];
    const float* b_hh       = (const float*)d_in[3];
    const float* g_emb      = (const float*)d_in[4];
    const float* emb_kernel = (const float*)d_in[5];
    const float* emb_down   = (const float*)d_in[6];
    const float* emb_up     = (const float*)d_in[7];
    const float* w_kernel   = (const float*)d_in[8];
    const float* w_down     = (const float*)d_in[9];
    const float* w_up       = (const float*)d_in[10];
    const float* noise      = (const float*)d_in[11];
    float* out = (float*)d_out;

    hipLaunchKernelGGL(controller_kernel, dim3(1), dim3(64), 0, stream,
                       w_ih, w_hh, b_ih, b_hh, g_emb, emb_kernel, emb_down,
                       emb_up, w_kernel, w_down, w_up, noise, out);
}